// Round 1
// baseline (306.697 us; speedup 1.0000x reference)
//
#include <hip/hip_runtime.h>
#include <math.h>

// Problem constants (match reference)
#define NB 1024            // batch
#define MP 8               // stripes per sample
#define DF 128             // feature dim
#define NV (NB*MP)         // 8192 local vectors
#define EPSR 1e-12f
#define MARGIN_ 0.3f

// GEMM tile config
#define TA 16              // a-samples per block
#define TB 16              // b-samples per block
#define KC 32              // k-chunk (floats)
#define KQ (KC/4)          // quads per row chunk

// ---------------------------------------------------------------------------
// Kernel 1: L2-normalize each of the 8192 local vectors; also store sq[v]
// (squared norm of the normalized vector, matching reference's sq = sum(xf*xf))
// One wave per vector (lane handles elements lane and lane+64).
// ---------------------------------------------------------------------------
__global__ __launch_bounds__(256) void norm_kernel(const float* __restrict__ x,
                                                   float* __restrict__ xn,
                                                   float* __restrict__ sq) {
    const int wave = threadIdx.x >> 6;
    const int lane = threadIdx.x & 63;
    const int v = blockIdx.x * 4 + wave;      // vector index [0, 8192)
    const float e0 = x[v * DF + lane];
    const float e1 = x[v * DF + 64 + lane];
    float s = e0 * e0 + e1 * e1;
    #pragma unroll
    for (int off = 32; off > 0; off >>= 1) s += __shfl_xor(s, off);
    const float inv = 1.0f / (sqrtf(s) + EPSR);
    xn[v * DF + lane]      = e0 * inv;
    xn[v * DF + 64 + lane] = e1 * inv;
    if (lane == 0) sq[v] = s * inv * inv;     // == ||x||^2 / (||x||+eps)^2
}

// ---------------------------------------------------------------------------
// Kernel 2: fused Gram + tanh-dist + 8x8 DTW DP.
// Block = 256 threads, tile = 16 a-samples x 16 b-samples. Thread t handles
// pair (aL = t&15, bL = t>>4): 8x8 = 64 dot products of dim 128, then the
// per-pair epilogue, writing dist_mat[aG][bG].
// LDS: A/B chunk tiles [128 vectors][32 floats], XOR-swizzled at float4
// granularity by (sample&7) so fragment reads are <=2-way bank-conflicted.
// ---------------------------------------------------------------------------
__global__ __launch_bounds__(256) void dist_kernel(const float* __restrict__ xn,
                                                   const float* __restrict__ sq,
                                                   float* __restrict__ dist) {
    __shared__ float As[TA * MP * KC];   // 16 KB
    __shared__ float Bs[TB * MP * KC];   // 16 KB

    const int t  = threadIdx.x;
    const int aL = t & 15;
    const int bL = t >> 4;
    const int aBase = blockIdx.x * TA;
    const int bBase = blockIdx.y * TB;

    float acc[8][8];
    #pragma unroll
    for (int m = 0; m < 8; ++m)
        #pragma unroll
        for (int n = 0; n < 8; ++n) acc[m][n] = 0.0f;

    for (int kc = 0; kc < DF; kc += KC) {
        // ---- stage chunk: 128 rows x 8 quads per side; 8 quad-writes/thread
        #pragma unroll
        for (int i = 0; i < 4; ++i) {
            const int f   = t + i * 256;           // [0, 1024)
            const int row = f >> 3;                // vector within tile [0,128)
            const int q   = f & 7;                 // quad within chunk row
            const int smp = row >> 3;              // sample within tile [0,16)
            const int pq  = (row << 3) + (q ^ (smp & 7));  // swizzled quad pos
            const int gvA = (aBase + smp) * MP + (row & 7);
            const int gvB = (bBase + smp) * MP + (row & 7);
            const float4 ga = *(const float4*)&xn[gvA * DF + kc + q * 4];
            const float4 gb = *(const float4*)&xn[gvB * DF + kc + q * 4];
            *(float4*)&As[pq << 2] = ga;
            *(float4*)&Bs[pq << 2] = gb;
        }
        __syncthreads();

        // ---- compute: per 4-k step, 16 ds_read_b128 + 256 v_fma per wave
        #pragma unroll
        for (int k4 = 0; k4 < KQ; ++k4) {
            float4 af[8], bf[8];
            #pragma unroll
            for (int m = 0; m < 8; ++m) {
                const int rowA = (aL << 3) + m;
                const int rowB = (bL << 3) + m;
                af[m] = *(const float4*)&As[((rowA << 3) + (k4 ^ (aL & 7))) << 2];
                bf[m] = *(const float4*)&Bs[((rowB << 3) + (k4 ^ (bL & 7))) << 2];
            }
            #pragma unroll
            for (int m = 0; m < 8; ++m)
                #pragma unroll
                for (int n = 0; n < 8; ++n) {
                    acc[m][n] = fmaf(af[m].x, bf[n].x, acc[m][n]);
                    acc[m][n] = fmaf(af[m].y, bf[n].y, acc[m][n]);
                    acc[m][n] = fmaf(af[m].z, bf[n].z, acc[m][n]);
                    acc[m][n] = fmaf(af[m].w, bf[n].w, acc[m][n]);
                }
        }
        __syncthreads();
    }

    // ---- fused epilogue: tanh-dist + monotone shortest path over 8x8
    const int aG = aBase + aL;
    const int bG = bBase + bL;
    float sa[8], sb[8];
    #pragma unroll
    for (int i = 0; i < 8; ++i) {
        sa[i] = sq[aG * MP + i];
        sb[i] = sq[bG * MP + i];
    }

    float rowv[8];
    // i = 0: cumulative sum over j
    {
        float c = 0.0f;
        #pragma unroll
        for (int j = 0; j < 8; ++j) {
            const float d2 = fmaxf(sa[0] + sb[j] - 2.0f * acc[0][j], EPSR);
            const float d  = sqrtf(d2);
            const float e  = __expf(d);
            const float td = (e - 1.0f) / (e + 1.0f);   // tanh(d/2)
            c += td;
            rowv[j] = c;
        }
    }
    #pragma unroll
    for (int i = 1; i < 8; ++i) {
        float carry = INFINITY;
        #pragma unroll
        for (int j = 0; j < 8; ++j) {
            const float d2 = fmaxf(sa[i] + sb[j] - 2.0f * acc[i][j], EPSR);
            const float d  = sqrtf(d2);
            const float e  = __expf(d);
            const float td = (e - 1.0f) / (e + 1.0f);
            const float v  = fminf(carry, rowv[j]) + td;
            rowv[j] = v;
            carry = v;
        }
    }
    dist[aG * NB + bG] = rowv[7];
}

// ---------------------------------------------------------------------------
// Kernel 3: hard mining per row. One wave per row; lanes stride columns.
// ---------------------------------------------------------------------------
__global__ __launch_bounds__(256) void mine_kernel(const float* __restrict__ dist,
                                                   const int* __restrict__ labels,
                                                   float* __restrict__ rowloss) {
    const int wave = threadIdx.x >> 6;
    const int lane = threadIdx.x & 63;
    const int a = blockIdx.x * 4 + wave;
    const int la = labels[a];
    float mx = -INFINITY;   // dist_ap
    float mn =  INFINITY;   // dist_an
    #pragma unroll
    for (int bb = 0; bb < NB / 64; ++bb) {
        const int b = bb * 64 + lane;
        const float d = dist[a * NB + b];
        if (labels[b] == la) mx = fmaxf(mx, d);
        else                 mn = fminf(mn, d);
    }
    #pragma unroll
    for (int off = 32; off > 0; off >>= 1) {
        mx = fmaxf(mx, __shfl_xor(mx, off));
        mn = fminf(mn, __shfl_xor(mn, off));
    }
    if (lane == 0) rowloss[a] = fmaxf(mx - mn + MARGIN_, 0.0f);
}

// ---------------------------------------------------------------------------
// Kernel 4: deterministic mean reduce -> d_out[0]
// ---------------------------------------------------------------------------
__global__ __launch_bounds__(256) void reduce_kernel(const float* __restrict__ rowloss,
                                                     float* __restrict__ out) {
    __shared__ float buf[4];
    const int wave = threadIdx.x >> 6;
    const int lane = threadIdx.x & 63;
    float s = 0.0f;
    for (int i = threadIdx.x; i < NB; i += 256) s += rowloss[i];
    #pragma unroll
    for (int off = 32; off > 0; off >>= 1) s += __shfl_xor(s, off);
    if (lane == 0) buf[wave] = s;
    __syncthreads();
    if (threadIdx.x == 0) {
        const float total = buf[0] + buf[1] + buf[2] + buf[3];
        out[0] = total * (1.0f / (float)NB);
    }
}

// ---------------------------------------------------------------------------
// Workspace layout (floats):
//   xn      [8192*128]  @ 0          (4 MB)
//   sq      [8192]      @ 1048576    (32 KB)
//   dist    [1024*1024] @ 1056768    (4 MB)
//   rowloss [1024]      @ 2105344    (4 KB)
// Total ~8.23 MB
// ---------------------------------------------------------------------------
extern "C" void kernel_launch(void* const* d_in, const int* in_sizes, int n_in,
                              void* d_out, int out_size, void* d_ws, size_t ws_size,
                              hipStream_t stream) {
    const float* x      = (const float*)d_in[0];
    const int*   labels = (const int*)d_in[1];
    float* out = (float*)d_out;
    float* ws  = (float*)d_ws;

    float* xn      = ws;
    float* sq      = ws + (size_t)NV * DF;
    float* dist    = sq + NV;
    float* rowloss = dist + (size_t)NB * NB;

    norm_kernel<<<NV / 4, 256, 0, stream>>>(x, xn, sq);
    dist_kernel<<<dim3(NB / TA, NB / TB), 256, 0, stream>>>(xn, sq, dist);
    mine_kernel<<<NB / 4, 256, 0, stream>>>(dist, labels, rowloss);
    reduce_kernel<<<1, 256, 0, stream>>>(rowloss, out);
}

// Round 2
// 138.142 us; speedup vs baseline: 2.2202x; 2.2202x over previous
//
#include <hip/hip_runtime.h>
#include <hip/hip_bf16.h>
#include <math.h>

// Problem constants (match reference)
#define NB 1024            // batch
#define MP 8               // stripes per sample
#define DF 128             // feature dim
#define NV (NB*MP)         // 8192 local vectors
#define EPSR 1e-12f
#define MARGIN_ 0.3f

typedef __bf16 bf16x8 __attribute__((ext_vector_type(8)));
typedef float  f32x4  __attribute__((ext_vector_type(4)));

// ---------------------------------------------------------------------------
// Kernel 1: L2-normalize each of the 8192 local vectors.
// Outputs: xnb (bf16 normalized vectors, for MFMA) and sq[v] = ||xf||^2 in fp32
// (matches reference's sq computed AFTER the eps-normalize).
// One wave per vector (lane handles elements lane and lane+64).
// ---------------------------------------------------------------------------
__global__ __launch_bounds__(256) void norm_kernel(const float* __restrict__ x,
                                                   unsigned short* __restrict__ xnb,
                                                   float* __restrict__ sq) {
    const int wave = threadIdx.x >> 6;
    const int lane = threadIdx.x & 63;
    const int v = blockIdx.x * 4 + wave;      // vector index [0, 8192)
    const float e0 = x[v * DF + lane];
    const float e1 = x[v * DF + 64 + lane];
    float s = e0 * e0 + e1 * e1;
    #pragma unroll
    for (int off = 32; off > 0; off >>= 1) s += __shfl_xor(s, off);
    const float inv = 1.0f / (sqrtf(s) + EPSR);
    const __hip_bfloat16 b0 = __float2bfloat16(e0 * inv);
    const __hip_bfloat16 b1 = __float2bfloat16(e1 * inv);
    xnb[v * DF + lane]      = *(const unsigned short*)&b0;
    xnb[v * DF + 64 + lane] = *(const unsigned short*)&b1;
    if (lane == 0) sq[v] = s * inv * inv;     // == ||x||^2 / (||x||+eps)^2
}

// ---------------------------------------------------------------------------
// Kernel 2: MFMA Gram + fused tanh-dist + 8x8 DTW DP.
// Block = 256 threads (4 waves), tile = 16 a-samples x 16 b-samples
// (= 128x128 vectors, K=128 fully staged in LDS as bf16).
// Wave w (wr=w>>1, wc=w&1) computes the 64x64 Gram quadrant
// [wr*64, +64) x [wc*64, +64) as 4x4 tiles of mfma_f32_16x16x32_bf16.
// Acc is written to LDS in pair-major swizzled fp32 layout (reusing the
// staging buffer), then thread t (aL=t>>4, bL=t&15) reads its 8x8 block and
// runs the fp32 epilogue, writing dist[aG][bG].
//
// LDS swizzle: 16B chunks XOR'd by low row bits -> every wave64 LDS op
// spreads evenly over banks (<=2-way, free per m136).
// ---------------------------------------------------------------------------
__global__ __launch_bounds__(256) void dist_kernel(const unsigned short* __restrict__ xnb,
                                                   const float* __restrict__ sq,
                                                   float* __restrict__ dist) {
    __shared__ alignas(16) unsigned char smem[65536];   // 64 KB (union)
    unsigned short* As = (unsigned short*)smem;          // 128 rows x 128 bf16 (32 KB)
    unsigned short* Bs = (unsigned short*)(smem + 32768);
    float* E = (float*)smem;                             // 128x128 fp32 Gram (64 KB)

    const int t    = threadIdx.x;
    const int wave = t >> 6;
    const int lane = t & 63;
    const int wr   = wave >> 1;
    const int wc   = wave & 1;
    const int aBase = blockIdx.x * 16;    // sample indices
    const int bBase = blockIdx.y * 16;

    // ---- stage A and B tiles: 128 rows x 16 chunks (16 B) each side
    #pragma unroll
    for (int i = 0; i < 8; ++i) {
        const int idx = t + i * 256;           // [0, 2048)
        const int row = idx >> 4;              // vector within tile [0,128)
        const int ch  = idx & 15;              // 16B chunk within row
        const int p   = ch ^ (row & 15);       // swizzled chunk position
        const uint4 va = *(const uint4*)&xnb[(aBase * MP + row) * DF + ch * 8];
        const uint4 vb = *(const uint4*)&xnb[(bBase * MP + row) * DF + ch * 8];
        *(uint4*)&As[row * DF + p * 8] = va;
        *(uint4*)&Bs[row * DF + p * 8] = vb;
    }
    __syncthreads();

    // ---- MFMA phase: 4 k-steps x 16 tiles per wave
    f32x4 acc[4][4];
    #pragma unroll
    for (int tr = 0; tr < 4; ++tr)
        #pragma unroll
        for (int tc = 0; tc < 4; ++tc) acc[tr][tc] = (f32x4){0.f, 0.f, 0.f, 0.f};

    const int fr = lane & 15;        // fragment row within 16
    const int fq = lane >> 4;        // quad -> k-subchunk
    #pragma unroll
    for (int ks = 0; ks < 4; ++ks) {
        bf16x8 af[4], bf[4];
        const int ch = ks * 4 + fq;
        #pragma unroll
        for (int tr = 0; tr < 4; ++tr) {
            const int va = wr * 64 + tr * 16 + fr;
            af[tr] = *(const bf16x8*)&As[va * DF + (ch ^ (va & 15)) * 8];
        }
        #pragma unroll
        for (int tc = 0; tc < 4; ++tc) {
            const int vb = wc * 64 + tc * 16 + fr;
            bf[tc] = *(const bf16x8*)&Bs[vb * DF + (ch ^ (vb & 15)) * 8];
        }
        #pragma unroll
        for (int tr = 0; tr < 4; ++tr)
            #pragma unroll
            for (int tc = 0; tc < 4; ++tc)
                acc[tr][tc] = __builtin_amdgcn_mfma_f32_16x16x32_bf16(
                    af[tr], bf[tc], acc[tr][tc], 0, 0, 0);
    }
    __syncthreads();   // all staging reads done before overwrite

    // ---- scatter acc -> pair-major swizzled fp32 layout in E
    // Reading thread t has aL = t>>4, bL = t&15; its 64-float block at t*64.
    // Element (i,j): chunk cc = (i*8+j)>>2, position p = cc ^ bL(= t&15).
    #pragma unroll
    for (int tr = 0; tr < 4; ++tr) {
        #pragma unroll
        for (int tc = 0; tc < 4; ++tc) {
            const int c  = wc * 64 + tc * 16 + fr;     // Gram col (b-vector)
            const int bL = c >> 3, j = c & 7;
            #pragma unroll
            for (int g = 0; g < 4; ++g) {
                const int r  = wr * 64 + tr * 16 + fq * 4 + g;  // Gram row (a-vector)
                const int aL = r >> 3, i = r & 7;
                const int cc = ((i << 3) + j) >> 2;
                const int p  = cc ^ bL;
                E[((aL << 4) + bL) * 64 + (p << 2) + (j & 3)] = acc[tr][tc][g];
            }
        }
    }
    __syncthreads();

    // ---- per-thread epilogue: gather 8x8 block (conflict-free), DP, store
    float g8[8][8];
    #pragma unroll
    for (int cc = 0; cc < 16; ++cc) {
        const int p = cc ^ (t & 15);
        const f32x4 v = *(const f32x4*)&E[t * 64 + p * 4];
        const int i = cc >> 1, jb = (cc & 1) * 4;
        g8[i][jb + 0] = v[0]; g8[i][jb + 1] = v[1];
        g8[i][jb + 2] = v[2]; g8[i][jb + 3] = v[3];
    }

    const int aG = aBase + (t >> 4);
    const int bG = bBase + (t & 15);
    float sa[8], sb[8];
    #pragma unroll
    for (int i = 0; i < 8; ++i) {
        sa[i] = sq[aG * MP + i];
        sb[i] = sq[bG * MP + i];
    }

    float rowv[8];
    {   // i = 0: cumulative sum over j
        float c = 0.0f;
        #pragma unroll
        for (int j = 0; j < 8; ++j) {
            const float d2 = fmaxf(sa[0] + sb[j] - 2.0f * g8[0][j], EPSR);
            const float d  = sqrtf(d2);
            const float e  = __expf(d);
            c += (e - 1.0f) / (e + 1.0f);   // tanh(d/2)
            rowv[j] = c;
        }
    }
    #pragma unroll
    for (int i = 1; i < 8; ++i) {
        float carry = INFINITY;
        #pragma unroll
        for (int j = 0; j < 8; ++j) {
            const float d2 = fmaxf(sa[i] + sb[j] - 2.0f * g8[i][j], EPSR);
            const float d  = sqrtf(d2);
            const float e  = __expf(d);
            const float td = (e - 1.0f) / (e + 1.0f);
            const float v  = fminf(carry, rowv[j]) + td;
            rowv[j] = v;
            carry = v;
        }
    }
    dist[aG * NB + bG] = rowv[7];
}

// ---------------------------------------------------------------------------
// Kernel 3: hard mining per row. One wave per row; lanes stride columns.
// ---------------------------------------------------------------------------
__global__ __launch_bounds__(256) void mine_kernel(const float* __restrict__ dist,
                                                   const int* __restrict__ labels,
                                                   float* __restrict__ rowloss) {
    const int wave = threadIdx.x >> 6;
    const int lane = threadIdx.x & 63;
    const int a = blockIdx.x * 4 + wave;
    const int la = labels[a];
    float mx = -INFINITY;   // dist_ap
    float mn =  INFINITY;   // dist_an
    #pragma unroll
    for (int bb = 0; bb < NB / 64; ++bb) {
        const int b = bb * 64 + lane;
        const float d = dist[a * NB + b];
        if (labels[b] == la) mx = fmaxf(mx, d);
        else                 mn = fminf(mn, d);
    }
    #pragma unroll
    for (int off = 32; off > 0; off >>= 1) {
        mx = fmaxf(mx, __shfl_xor(mx, off));
        mn = fminf(mn, __shfl_xor(mn, off));
    }
    if (lane == 0) rowloss[a] = fmaxf(mx - mn + MARGIN_, 0.0f);
}

// ---------------------------------------------------------------------------
// Kernel 4: deterministic mean reduce -> d_out[0]
// ---------------------------------------------------------------------------
__global__ __launch_bounds__(256) void reduce_kernel(const float* __restrict__ rowloss,
                                                     float* __restrict__ out) {
    __shared__ float buf[4];
    const int wave = threadIdx.x >> 6;
    const int lane = threadIdx.x & 63;
    float s = 0.0f;
    for (int i = threadIdx.x; i < NB; i += 256) s += rowloss[i];
    #pragma unroll
    for (int off = 32; off > 0; off >>= 1) s += __shfl_xor(s, off);
    if (lane == 0) buf[wave] = s;
    __syncthreads();
    if (threadIdx.x == 0) {
        out[0] = (buf[0] + buf[1] + buf[2] + buf[3]) * (1.0f / (float)NB);
    }
}

// ---------------------------------------------------------------------------
// Workspace layout:
//   xnb     [8192*128] ushort @ 0        (2 MB)
//   sq      [8192]     float             (32 KB)
//   dist    [1024*1024] float            (4 MB)
//   rowloss [1024]     float             (4 KB)
// ---------------------------------------------------------------------------
extern "C" void kernel_launch(void* const* d_in, const int* in_sizes, int n_in,
                              void* d_out, int out_size, void* d_ws, size_t ws_size,
                              hipStream_t stream) {
    const float* x      = (const float*)d_in[0];
    const int*   labels = (const int*)d_in[1];
    float* out = (float*)d_out;

    unsigned short* xnb = (unsigned short*)d_ws;
    float* sq      = (float*)(xnb + (size_t)NV * DF);
    float* dist    = sq + NV;
    float* rowloss = dist + (size_t)NB * NB;

    norm_kernel<<<NV / 4, 256, 0, stream>>>(x, xnb, sq);
    dist_kernel<<<dim3(NB / 16, NB / 16), 256, 0, stream>>>(xnb, sq, dist);
    mine_kernel<<<NB / 4, 256, 0, stream>>>(dist, labels, rowloss);
    reduce_kernel<<<1, 256, 0, stream>>>(rowloss, out);
}

// Round 3
// 91.535 us; speedup vs baseline: 3.3506x; 1.5092x over previous
//
#include <hip/hip_runtime.h>
#include <hip/hip_bf16.h>
#include <math.h>

// Problem constants (match reference)
#define NB 1024            // batch
#define MP 8               // stripes per sample
#define DF 128             // feature dim
#define NV (NB*MP)         // 8192 local vectors
#define EPSR 1e-12f
#define MARGIN_ 0.3f

typedef __bf16 bf16x8 __attribute__((ext_vector_type(8)));
typedef float  f32x4  __attribute__((ext_vector_type(4)));

// ---------------------------------------------------------------------------
// Kernel 1: L2-normalize each of the 8192 local vectors.
// Outputs: xnb (bf16 normalized, for MFMA), sq[v] = ||xf||^2 (fp32, matches
// reference's post-eps-normalize squared norm). Also zeroes out[0] so the
// mining kernel can atomicAdd into it (harness poisons d_out each launch).
// ---------------------------------------------------------------------------
__global__ __launch_bounds__(256) void norm_kernel(const float* __restrict__ x,
                                                   unsigned short* __restrict__ xnb,
                                                   float* __restrict__ sq,
                                                   float* __restrict__ out) {
    if (blockIdx.x == 0 && threadIdx.x == 0) out[0] = 0.0f;
    const int wave = threadIdx.x >> 6;
    const int lane = threadIdx.x & 63;
    const int v = blockIdx.x * 4 + wave;      // vector index [0, 8192)
    const float e0 = x[v * DF + lane];
    const float e1 = x[v * DF + 64 + lane];
    float s = e0 * e0 + e1 * e1;
    #pragma unroll
    for (int off = 32; off > 0; off >>= 1) s += __shfl_xor(s, off);
    const float inv = 1.0f / (sqrtf(s) + EPSR);
    const __hip_bfloat16 b0 = __float2bfloat16(e0 * inv);
    const __hip_bfloat16 b1 = __float2bfloat16(e1 * inv);
    xnb[v * DF + lane]      = *(const unsigned short*)&b0;
    xnb[v * DF + 64 + lane] = *(const unsigned short*)&b1;
    if (lane == 0) sq[v] = s * inv * inv;
}

// ---------------------------------------------------------------------------
// Kernel 2: MFMA Gram + fused tanh-dist + 8x8 DTW DP, upper-triangular tiles.
// The DTW distance is symmetric (recurrence invariant under transpose), so
// only tile pairs bx <= by are computed; results mirrored to dist[b][a].
// Block = 256 threads (4 waves), tile = 16x16 samples = 128x128 vectors,
// K=128 fully staged in LDS as bf16. Wave w = (wr,wc) computes a 64x64 Gram
// quadrant via 4x4 mfma_f32_16x16x32_bf16 tiles.
// Gram round-trip through LDS uses per-pair 64-float blocks, COL-MAJOR
// (element (i,j) at j*8+i) so each acc f32x4 (4 consecutive rows, one col)
// is a single ds_write_b128. Chunk position XOR-swizzled by bL -> 8 start
// banks x 8 lanes for both scatter and gather = conflict-free.
// ---------------------------------------------------------------------------
__global__ __launch_bounds__(256) void dist_kernel(const unsigned short* __restrict__ xnb,
                                                   const float* __restrict__ sq,
                                                   float* __restrict__ dist) {
    __shared__ alignas(16) unsigned char smem[65536];   // 64 KB (union)
    unsigned short* As = (unsigned short*)smem;          // 128 x 128 bf16 (32 KB)
    unsigned short* Bs = (unsigned short*)(smem + 32768);
    float* E = (float*)smem;                             // 256 pair-blocks x 64 fp32

    // triangular decode: blockIdx.x -> (bx <= by)
    const int idx = (int)blockIdx.x;
    float fsq = sqrtf(8.0f * (float)idx + 1.0f);
    int by = (int)((fsq - 1.0f) * 0.5f);
    while ((by + 1) * (by + 2) / 2 <= idx) ++by;
    while (by * (by + 1) / 2 > idx) --by;
    const int bx = idx - by * (by + 1) / 2;

    const int t    = threadIdx.x;
    const int wave = t >> 6;
    const int lane = t & 63;
    const int wr   = wave >> 1;
    const int wc   = wave & 1;
    const int aBase = bx * 16;    // sample indices
    const int bBase = by * 16;

    // ---- stage A and B tiles: 128 rows x 16 chunks (16 B) each side
    #pragma unroll
    for (int i = 0; i < 8; ++i) {
        const int ldi = t + i * 256;           // [0, 2048)
        const int row = ldi >> 4;              // vector within tile [0,128)
        const int ch  = ldi & 15;              // 16B chunk within row
        const int p   = ch ^ (row & 15);       // swizzled chunk position
        const uint4 va = *(const uint4*)&xnb[(aBase * MP + row) * DF + ch * 8];
        const uint4 vb = *(const uint4*)&xnb[(bBase * MP + row) * DF + ch * 8];
        *(uint4*)&As[row * DF + p * 8] = va;
        *(uint4*)&Bs[row * DF + p * 8] = vb;
    }
    __syncthreads();

    // ---- MFMA phase: 4 k-steps x 16 tiles per wave
    f32x4 acc[4][4];
    #pragma unroll
    for (int tr = 0; tr < 4; ++tr)
        #pragma unroll
        for (int tc = 0; tc < 4; ++tc) acc[tr][tc] = (f32x4){0.f, 0.f, 0.f, 0.f};

    const int fr = lane & 15;        // fragment row within 16
    const int fq = lane >> 4;        // quad
    #pragma unroll
    for (int ks = 0; ks < 4; ++ks) {
        bf16x8 af[4], bfr[4];
        const int ch = ks * 4 + fq;
        #pragma unroll
        for (int tr = 0; tr < 4; ++tr) {
            const int va = wr * 64 + tr * 16 + fr;
            af[tr] = *(const bf16x8*)&As[va * DF + (ch ^ fr) * 8];
        }
        #pragma unroll
        for (int tc = 0; tc < 4; ++tc) {
            const int vb = wc * 64 + tc * 16 + fr;
            bfr[tc] = *(const bf16x8*)&Bs[vb * DF + (ch ^ fr) * 8];
        }
        #pragma unroll
        for (int tr = 0; tr < 4; ++tr)
            #pragma unroll
            for (int tc = 0; tc < 4; ++tc)
                acc[tr][tc] = __builtin_amdgcn_mfma_f32_16x16x32_bf16(
                    af[tr], bfr[tc], acc[tr][tc], 0, 0, 0);
    }
    __syncthreads();   // staging reads done before E overwrites

    // ---- scatter acc -> per-pair col-major blocks, one b128 per (tr,tc)
    // C/D layout: col c = wc*64+tc*16+fr; rows r = wr*64+tr*16+fq*4+{0..3}.
    #pragma unroll
    for (int tr = 0; tr < 4; ++tr) {
        const int r0 = wr * 64 + tr * 16 + fq * 4;
        const int aL = r0 >> 3;
        const int cqr = fq & 1;                 // i>>2 within 8-row block
        #pragma unroll
        for (int tc = 0; tc < 4; ++tc) {
            const int c  = wc * 64 + tc * 16 + fr;
            const int bL = c >> 3, j = c & 7;
            const int cq = (j << 1) | cqr;      // chunk = col j, row-half
            const int p  = (cq ^ bL) & 15;      // swizzled chunk position
            *(f32x4*)&E[(((aL << 4) + bL) << 6) + (p << 2)] = acc[tr][tc];
        }
    }
    __syncthreads();

    // ---- per-thread gather (conflict-free) + fp32 epilogue
    float g8[8][8];
    {
        const int bL = t & 15;
        #pragma unroll
        for (int cq = 0; cq < 16; ++cq) {
            const int p = (cq ^ bL) & 15;
            const f32x4 v = *(const f32x4*)&E[(t << 6) + (p << 2)];
            const int j = cq >> 1, ib = (cq & 1) * 4;
            g8[ib + 0][j] = v[0]; g8[ib + 1][j] = v[1];
            g8[ib + 2][j] = v[2]; g8[ib + 3][j] = v[3];
        }
    }

    const int aG = aBase + (t >> 4);
    const int bG = bBase + (t & 15);
    float sa[8], sb[8];
    #pragma unroll
    for (int i = 0; i < 8; ++i) {
        sa[i] = sq[aG * MP + i];
        sb[i] = sq[bG * MP + i];
    }

    float rowv[8];
    {   // i = 0: cumulative sum over j
        float c = 0.0f;
        #pragma unroll
        for (int j = 0; j < 8; ++j) {
            const float d2 = fmaxf(fmaf(-2.0f, g8[0][j], sa[0] + sb[j]), EPSR);
            const float d  = __builtin_amdgcn_sqrtf(d2);
            const float e  = __builtin_amdgcn_exp2f(d * 1.44269504f);
            c += fmaf(-2.0f, __builtin_amdgcn_rcpf(e + 1.0f), 1.0f);
            rowv[j] = c;
        }
    }
    #pragma unroll
    for (int i = 1; i < 8; ++i) {
        float carry = INFINITY;
        const float sai = sa[i];
        #pragma unroll
        for (int j = 0; j < 8; ++j) {
            const float d2 = fmaxf(fmaf(-2.0f, g8[i][j], sai + sb[j]), EPSR);
            const float d  = __builtin_amdgcn_sqrtf(d2);
            const float e  = __builtin_amdgcn_exp2f(d * 1.44269504f);
            const float td = fmaf(-2.0f, __builtin_amdgcn_rcpf(e + 1.0f), 1.0f);
            const float v  = fminf(carry, rowv[j]) + td;
            rowv[j] = v;
            carry = v;
        }
    }
    dist[aG * NB + bG] = rowv[7];
    if (bx != by) dist[bG * NB + aG] = rowv[7];   // symmetric mirror
}

// ---------------------------------------------------------------------------
// Kernel 3: hard mining per row + fused mean reduce (atomicAdd into out[0],
// which norm_kernel zeroed at the head of the stream).
// ---------------------------------------------------------------------------
__global__ __launch_bounds__(256) void mine_kernel(const float* __restrict__ dist,
                                                   const int* __restrict__ labels,
                                                   float* __restrict__ out) {
    __shared__ float buf[4];
    const int wave = threadIdx.x >> 6;
    const int lane = threadIdx.x & 63;
    const int a = blockIdx.x * 4 + wave;
    const int la = labels[a];
    float mx = -INFINITY;   // dist_ap
    float mn =  INFINITY;   // dist_an
    #pragma unroll
    for (int bb = 0; bb < NB / 64; ++bb) {
        const int b = bb * 64 + lane;
        const float d = dist[a * NB + b];
        if (labels[b] == la) mx = fmaxf(mx, d);
        else                 mn = fminf(mn, d);
    }
    #pragma unroll
    for (int off = 32; off > 0; off >>= 1) {
        mx = fmaxf(mx, __shfl_xor(mx, off));
        mn = fminf(mn, __shfl_xor(mn, off));
    }
    if (lane == 0) buf[wave] = fmaxf(mx - mn + MARGIN_, 0.0f);
    __syncthreads();
    if (threadIdx.x == 0) {
        atomicAdd(out, (buf[0] + buf[1] + buf[2] + buf[3]) * (1.0f / (float)NB));
    }
}

// ---------------------------------------------------------------------------
// Workspace layout:
//   xnb     [8192*128] ushort   (2 MB)
//   sq      [8192]     float    (32 KB)
//   dist    [1024*1024] float   (4 MB)
// ---------------------------------------------------------------------------
extern "C" void kernel_launch(void* const* d_in, const int* in_sizes, int n_in,
                              void* d_out, int out_size, void* d_ws, size_t ws_size,
                              hipStream_t stream) {
    const float* x      = (const float*)d_in[0];
    const int*   labels = (const int*)d_in[1];
    float* out = (float*)d_out;

    unsigned short* xnb = (unsigned short*)d_ws;
    float* sq   = (float*)(xnb + (size_t)NV * DF);
    float* dist = sq + NV;

    const int ntiles = (NB / 16) * (NB / 16 + 1) / 2;   // 2080

    norm_kernel<<<NV / 4, 256, 0, stream>>>(x, xnb, sq, out);
    dist_kernel<<<ntiles, 256, 0, stream>>>(xnb, sq, dist);
    mine_kernel<<<NB / 4, 256, 0, stream>>>(dist, labels, out);
}

// Round 4
// 87.884 us; speedup vs baseline: 3.4898x; 1.0416x over previous
//
#include <hip/hip_runtime.h>
#include <hip/hip_bf16.h>
#include <math.h>

// Problem constants (match reference)
#define NB 1024            // batch
#define MP 8               // stripes per sample
#define DF 128             // feature dim
#define NV (NB*MP)         // 8192 local vectors
#define EPSR 1e-12f
#define MARGIN_ 0.3f

// Degree-4 Chebyshev interpolant of g(y) = tanh(sqrt(y)/2)/sqrt(y) on [0,4].
// tanh(sqrt(y)/2) = sqrt(y) * g(y). Max |err| ~1e-4 over [0,4] (hand-checked
// at y = 0.25/0.5/1/2/3/3.9/4 against exact values).
#define GC0  0.4999965f
#define GC1 -0.0416276f
#define GC2  0.0040808f
#define GC3 -0.00035138f
#define GC4  0.00001765f

typedef __bf16 bf16x8 __attribute__((ext_vector_type(8)));
typedef float  f32x4  __attribute__((ext_vector_type(4)));

// ---------------------------------------------------------------------------
// Kernel 1: L2-normalize each of the 8192 local vectors.
// Outputs: xnb (bf16 normalized, for MFMA), sq[v] = ||xf||^2 (fp32, matches
// reference's post-eps-normalize squared norm). Also zeroes out[0] so the
// mining kernel can atomicAdd into it (harness poisons d_out each launch).
// ---------------------------------------------------------------------------
__global__ __launch_bounds__(256) void norm_kernel(const float* __restrict__ x,
                                                   unsigned short* __restrict__ xnb,
                                                   float* __restrict__ sq,
                                                   float* __restrict__ out) {
    if (blockIdx.x == 0 && threadIdx.x == 0) out[0] = 0.0f;
    const int wave = threadIdx.x >> 6;
    const int lane = threadIdx.x & 63;
    const int v = blockIdx.x * 4 + wave;      // vector index [0, 8192)
    const float e0 = x[v * DF + lane];
    const float e1 = x[v * DF + 64 + lane];
    float s = e0 * e0 + e1 * e1;
    #pragma unroll
    for (int off = 32; off > 0; off >>= 1) s += __shfl_xor(s, off);
    const float inv = 1.0f / (sqrtf(s) + EPSR);
    const __hip_bfloat16 b0 = __float2bfloat16(e0 * inv);
    const __hip_bfloat16 b1 = __float2bfloat16(e1 * inv);
    xnb[v * DF + lane]      = *(const unsigned short*)&b0;
    xnb[v * DF + 64 + lane] = *(const unsigned short*)&b1;
    if (lane == 0) sq[v] = s * inv * inv;
}

// ---------------------------------------------------------------------------
// Kernel 2: MFMA Gram + fused tanh-dist + 8x8 DTW DP, upper-triangular tiles.
// DTW distance is symmetric -> only bx <= by tiles computed, mirror-written.
// Block = 256 threads (4 waves), tile = 16x16 samples = 128x128 vectors,
// K=128 staged in LDS as bf16. Wave (wr,wc) computes a 64x64 Gram quadrant
// via 4x4 mfma_f32_16x16x32_bf16 tiles. Gram round-trips through LDS in
// per-pair col-major 64-float blocks (one ds_write_b128 per acc f32x4);
// chunk position XOR-swizzled by bL -> conflict-free scatter and gather.
// Epilogue: tanh(sqrt(d2)/2) via sqrt * poly4(d2)  (1 transcendental instead
// of sqrt+exp+rcp), computed during the gather; DP is pure min+add.
// ---------------------------------------------------------------------------
__global__ __launch_bounds__(256) void dist_kernel(const unsigned short* __restrict__ xnb,
                                                   const float* __restrict__ sq,
                                                   float* __restrict__ dist) {
    __shared__ alignas(16) unsigned char smem[65536];   // 64 KB (union)
    unsigned short* As = (unsigned short*)smem;          // 128 x 128 bf16 (32 KB)
    unsigned short* Bs = (unsigned short*)(smem + 32768);
    float* E = (float*)smem;                             // 256 pair-blocks x 64 fp32

    // triangular decode: blockIdx.x -> (bx <= by)
    const int idx = (int)blockIdx.x;
    float fsq = sqrtf(8.0f * (float)idx + 1.0f);
    int by = (int)((fsq - 1.0f) * 0.5f);
    while ((by + 1) * (by + 2) / 2 <= idx) ++by;
    while (by * (by + 1) / 2 > idx) --by;
    const int bx = idx - by * (by + 1) / 2;

    const int t    = threadIdx.x;
    const int wave = t >> 6;
    const int lane = t & 63;
    const int wr   = wave >> 1;
    const int wc   = wave & 1;
    const int aBase = bx * 16;    // sample indices
    const int bBase = by * 16;

    // ---- stage A and B tiles: 128 rows x 16 chunks (16 B) each side
    #pragma unroll
    for (int i = 0; i < 8; ++i) {
        const int ldi = t + i * 256;           // [0, 2048)
        const int row = ldi >> 4;              // vector within tile [0,128)
        const int ch  = ldi & 15;              // 16B chunk within row
        const int p   = ch ^ (row & 15);       // swizzled chunk position
        const uint4 va = *(const uint4*)&xnb[(aBase * MP + row) * DF + ch * 8];
        const uint4 vb = *(const uint4*)&xnb[(bBase * MP + row) * DF + ch * 8];
        *(uint4*)&As[row * DF + p * 8] = va;
        *(uint4*)&Bs[row * DF + p * 8] = vb;
    }
    __syncthreads();

    // ---- MFMA phase: 4 k-steps x 16 tiles per wave
    f32x4 acc[4][4];
    #pragma unroll
    for (int tr = 0; tr < 4; ++tr)
        #pragma unroll
        for (int tc = 0; tc < 4; ++tc) acc[tr][tc] = (f32x4){0.f, 0.f, 0.f, 0.f};

    const int fr = lane & 15;        // fragment row within 16
    const int fq = lane >> 4;        // quad
    #pragma unroll
    for (int ks = 0; ks < 4; ++ks) {
        bf16x8 af[4], bfr[4];
        const int ch = ks * 4 + fq;
        #pragma unroll
        for (int tr = 0; tr < 4; ++tr) {
            const int va = wr * 64 + tr * 16 + fr;
            af[tr] = *(const bf16x8*)&As[va * DF + (ch ^ fr) * 8];
        }
        #pragma unroll
        for (int tc = 0; tc < 4; ++tc) {
            const int vb = wc * 64 + tc * 16 + fr;
            bfr[tc] = *(const bf16x8*)&Bs[vb * DF + (ch ^ fr) * 8];
        }
        #pragma unroll
        for (int tr = 0; tr < 4; ++tr)
            #pragma unroll
            for (int tc = 0; tc < 4; ++tc)
                acc[tr][tc] = __builtin_amdgcn_mfma_f32_16x16x32_bf16(
                    af[tr], bfr[tc], acc[tr][tc], 0, 0, 0);
    }
    __syncthreads();   // staging reads done before E overwrites

    // ---- scatter acc -> per-pair col-major blocks, one b128 per (tr,tc)
    // C/D layout: col c = wc*64+tc*16+fr; rows r = wr*64+tr*16+fq*4+{0..3}.
    #pragma unroll
    for (int tr = 0; tr < 4; ++tr) {
        const int r0 = wr * 64 + tr * 16 + fq * 4;
        const int aL = r0 >> 3;
        const int cqr = fq & 1;                 // i>>2 within 8-row block
        #pragma unroll
        for (int tc = 0; tc < 4; ++tc) {
            const int c  = wc * 64 + tc * 16 + fr;
            const int bL = c >> 3, j = c & 7;
            const int cq = (j << 1) | cqr;      // chunk = col j, row-half
            const int p  = (cq ^ bL) & 15;      // swizzled chunk position
            *(f32x4*)&E[(((aL << 4) + bL) << 6) + (p << 2)] = acc[tr][tc];
        }
    }
    __syncthreads();

    const int aG = aBase + (t >> 4);
    const int bG = bBase + (t & 15);
    float sa[8], sb[8];
    #pragma unroll
    for (int i = 0; i < 8; ++i) {
        sa[i] = sq[aG * MP + i];
        sb[i] = sq[bG * MP + i];
    }

    // ---- gather (conflict-free) fused with tanh-dist conversion
    float g8[8][8];   // g8[i][j] = tanh(sqrt(d2_ij)/2)
    {
        const int bL = t & 15;
        #pragma unroll
        for (int cq = 0; cq < 16; ++cq) {
            const int p = (cq ^ bL) & 15;
            const f32x4 v = *(const f32x4*)&E[(t << 6) + (p << 2)];
            const int j = cq >> 1, ib = (cq & 1) * 4;
            #pragma unroll
            for (int g = 0; g < 4; ++g) {
                const int i = ib + g;
                const float d2 = fmaxf(fmaf(-2.0f, v[g], sa[i] + sb[j]), EPSR);
                const float d  = __builtin_amdgcn_sqrtf(d2);
                const float pg = fmaf(fmaf(fmaf(fmaf(GC4, d2, GC3), d2, GC2),
                                           d2, GC1), d2, GC0);
                g8[i][j] = d * pg;
            }
        }
    }

    // ---- DTW DP: pure min+add over precomputed g8
    float rowv[8];
    {
        float c = 0.0f;
        #pragma unroll
        for (int j = 0; j < 8; ++j) { c += g8[0][j]; rowv[j] = c; }
    }
    #pragma unroll
    for (int i = 1; i < 8; ++i) {
        float carry = INFINITY;
        #pragma unroll
        for (int j = 0; j < 8; ++j) {
            const float v = fminf(carry, rowv[j]) + g8[i][j];
            rowv[j] = v;
            carry = v;
        }
    }
    dist[aG * NB + bG] = rowv[7];
    if (bx != by) dist[bG * NB + aG] = rowv[7];   // symmetric mirror
}

// ---------------------------------------------------------------------------
// Kernel 3: hard mining per row + fused mean reduce (atomicAdd into out[0],
// which norm_kernel zeroed at the head of the stream).
// ---------------------------------------------------------------------------
__global__ __launch_bounds__(256) void mine_kernel(const float* __restrict__ dist,
                                                   const int* __restrict__ labels,
                                                   float* __restrict__ out) {
    __shared__ float buf[4];
    const int wave = threadIdx.x >> 6;
    const int lane = threadIdx.x & 63;
    const int a = blockIdx.x * 4 + wave;
    const int la = labels[a];
    float mx = -INFINITY;   // dist_ap
    float mn =  INFINITY;   // dist_an
    #pragma unroll
    for (int bb = 0; bb < NB / 64; ++bb) {
        const int b = bb * 64 + lane;
        const float d = dist[a * NB + b];
        if (labels[b] == la) mx = fmaxf(mx, d);
        else                 mn = fminf(mn, d);
    }
    #pragma unroll
    for (int off = 32; off > 0; off >>= 1) {
        mx = fmaxf(mx, __shfl_xor(mx, off));
        mn = fminf(mn, __shfl_xor(mn, off));
    }
    if (lane == 0) buf[wave] = fmaxf(mx - mn + MARGIN_, 0.0f);
    __syncthreads();
    if (threadIdx.x == 0) {
        atomicAdd(out, (buf[0] + buf[1] + buf[2] + buf[3]) * (1.0f / (float)NB));
    }
}

// ---------------------------------------------------------------------------
// Workspace layout:
//   xnb     [8192*128] ushort   (2 MB)
//   sq      [8192]     float    (32 KB)
//   dist    [1024*1024] float   (4 MB)
// ---------------------------------------------------------------------------
extern "C" void kernel_launch(void* const* d_in, const int* in_sizes, int n_in,
                              void* d_out, int out_size, void* d_ws, size_t ws_size,
                              hipStream_t stream) {
    const float* x      = (const float*)d_in[0];
    const int*   labels = (const int*)d_in[1];
    float* out = (float*)d_out;

    unsigned short* xnb = (unsigned short*)d_ws;
    float* sq   = (float*)(xnb + (size_t)NV * DF);
    float* dist = sq + NV;

    const int ntiles = (NB / 16) * (NB / 16 + 1) / 2;   // 2080

    norm_kernel<<<NV / 4, 256, 0, stream>>>(x, xnb, sq, out);
    dist_kernel<<<ntiles, 256, 0, stream>>>(xnb, sq, dist);
    mine_kernel<<<NB / 4, 256, 0, stream>>>(dist, labels, out);
}